// Round 12
// baseline (949.582 us; speedup 1.0000x reference)
//
#include <hip/hip_runtime.h>
#include <hip/hip_bf16.h>
#include <stdint.h>

// ExpanderLinear: y[t,o] = sum_i x[t,i] * (w[o,i]*mask[o,i]) + bias[o]
// M=8192, K=4096, N=4096. f32 in/out. INT8 MFMA path (R11, passed 0.039).
// R12 change: ring-4 (128KB LDS, 1 block/CU) -> ring-2 (64KB LDS, 2 blocks/CU)
// to enable cross-block MFMA/LDS pipe overlap (m114/m97 mechanism). Both
// stage batches issue at tile top (aged a full tile before the WVM0 drain).

typedef __attribute__((ext_vector_type(4))) float f32x4;
typedef __attribute__((ext_vector_type(4))) int   i32x4;

static constexpr int M = 8192;
static constexpr int N = 4096;
static constexpr int K = 4096;
static constexpr int NT = K / 64;      // 64 K-tiles

#define GLOBAL_AS(p) ((const __attribute__((address_space(1))) void*)(p))
#define LDS_AS(p)    ((__attribute__((address_space(3))) void*)(p))

// ---- prep 1: per-row quant of x -> i8 + sx ----
__global__ void __launch_bounds__(256)
quant_x(const float* __restrict__ x, signed char* __restrict__ xq,
        float* __restrict__ sx) {
    const int row = blockIdx.x, tid = threadIdx.x;
    const f32x4* xr = (const f32x4*)(x + (size_t)row * K);
    f32x4 v[4];
    float am = 0.0f;
#pragma unroll
    for (int c = 0; c < 4; ++c) {
        v[c] = xr[c * 256 + tid];
        am = fmaxf(am, fmaxf(fmaxf(fabsf(v[c].x), fabsf(v[c].y)),
                             fmaxf(fabsf(v[c].z), fabsf(v[c].w))));
    }
#pragma unroll
    for (int off = 32; off; off >>= 1) am = fmaxf(am, __shfl_xor(am, off));
    __shared__ float red[4];
    if ((tid & 63) == 0) red[tid >> 6] = am;
    __syncthreads();
    am = fmaxf(fmaxf(red[0], red[1]), fmaxf(red[2], red[3]));
    const float inv = am > 0.0f ? 127.0f / am : 0.0f;
    int* out = (int*)xq + (size_t)row * (K / 4);
#pragma unroll
    for (int c = 0; c < 4; ++c) {
        int q0 = (int)__builtin_rintf(v[c].x * inv) & 255;
        int q1 = (int)__builtin_rintf(v[c].y * inv) & 255;
        int q2 = (int)__builtin_rintf(v[c].z * inv) & 255;
        int q3 = (int)__builtin_rintf(v[c].w * inv) & 255;
        out[c * 256 + tid] = q0 | (q1 << 8) | (q2 << 16) | (q3 << 24);
    }
    if (tid == 0) sx[row] = am * (1.0f / 127.0f);
}

// ---- prep 2: per-row quant of (w*mask) -> i8 + sw ----
__global__ void __launch_bounds__(256)
quant_w(const float* __restrict__ w, const int* __restrict__ mask,
        signed char* __restrict__ wq, float* __restrict__ sw) {
    const int row = blockIdx.x, tid = threadIdx.x;
    const f32x4* wr = (const f32x4*)(w + (size_t)row * K);
    const i32x4* mr = (const i32x4*)(mask + (size_t)row * K);
    f32x4 v[4];
    float am = 0.0f;
#pragma unroll
    for (int c = 0; c < 4; ++c) {
        f32x4 wv = wr[c * 256 + tid];
        i32x4 mv = mr[c * 256 + tid];
        v[c].x = mv.x ? wv.x : 0.0f;
        v[c].y = mv.y ? wv.y : 0.0f;
        v[c].z = mv.z ? wv.z : 0.0f;
        v[c].w = mv.w ? wv.w : 0.0f;
        am = fmaxf(am, fmaxf(fmaxf(fabsf(v[c].x), fabsf(v[c].y)),
                             fmaxf(fabsf(v[c].z), fabsf(v[c].w))));
    }
#pragma unroll
    for (int off = 32; off; off >>= 1) am = fmaxf(am, __shfl_xor(am, off));
    __shared__ float red[4];
    if ((tid & 63) == 0) red[tid >> 6] = am;
    __syncthreads();
    am = fmaxf(fmaxf(red[0], red[1]), fmaxf(red[2], red[3]));
    const float inv = am > 0.0f ? 127.0f / am : 0.0f;
    int* out = (int*)wq + (size_t)row * (K / 4);
#pragma unroll
    for (int c = 0; c < 4; ++c) {
        int q0 = (int)__builtin_rintf(v[c].x * inv) & 255;
        int q1 = (int)__builtin_rintf(v[c].y * inv) & 255;
        int q2 = (int)__builtin_rintf(v[c].z * inv) & 255;
        int q3 = (int)__builtin_rintf(v[c].w * inv) & 255;
        out[c * 256 + tid] = q0 | (q1 << 8) | (q2 << 16) | (q3 << 24);
    }
    if (tid == 0) sw[row] = am * (1.0f / 127.0f);
}

// ---- main GEMM (i8) ----
// LDS: A = 2 units of [256 rows][64 B] (16KB each), B same -> 64 KiB total,
// 2 blocks/CU. Tile t in slot t&1; stage t+1 into slot (t&1)^1 at tile top
// (WAR-safe: slot's reads were consumed before the previous end-barrier).
// WVM0 at tile end waits on loads aged a full tile (~2600 cyc, no stall).
// Per K-tile 2 phases: {reads; BAR; 16 MFMA; BAR} x2 (R6/R11 pacing).
// Swizzle within 128B row-pair: phys3 = (((row&1)<<2)|fq) ^ ((row>>1)&7);
// LDS writes linear (global_load_lds); global SOURCE pre-swizzled (s3w).
__global__ void __launch_bounds__(512, 4)
gemmI8(const signed char* __restrict__ A,   // [M][K] i8
       const signed char* __restrict__ B,   // [N][K] i8
       const float* __restrict__ sx,        // [M]
       const float* __restrict__ sw,        // [N]
       const float* __restrict__ bias,      // [N]
       float* __restrict__ C) {             // [M][N] f32
    extern __shared__ unsigned char lds[];
    unsigned char* __restrict__ Au = lds;            // 2 * 16384 B
    unsigned char* __restrict__ Bu = lds + 32768;    // 2 * 16384 B

    const int tid  = threadIdx.x;
    const int lane = tid & 63;
    const int wave = tid >> 6;

    // T1: XCD-aware bijective swizzle (nwg = 512, % 8 == 0)
    const int bid = blockIdx.x;
    const int swz = (bid & 7) * 64 + (bid >> 3);
    const int brow = (swz >> 4) * 256;         // ntn = 16
    const int bcol = (swz & 15) * 256;

    const int wrow = (wave >> 2) * 128;        // wave output rows
    const int wcol = (wave & 3) * 64;          // wave output cols
    const int fr = lane & 15;                  // fragment row/col
    const int fq = lane >> 4;                  // k-subgroup (16B each)

    // read-side swizzle bases (byte offsets within a 16KB unit)
    const int s3r   = (((fr & 1) << 2) | fq) ^ (fr >> 1);
    const int abase = wrow * 64 + (fr >> 1) * 128 + s3r * 16;   // + m*1024
    const int bbase = wcol * 64 + (fr >> 1) * 128 + s3r * 16;   // + n*1024

    // write-side: lane's linear LDS slot -> logical (row, byte-col) in global
    const int l8 = lane & 7, lh = lane >> 3;
    const int s3w    = l8 ^ lh;
    const int wrow_l = 2 * lh + (s3w >> 2);    // row within 16-row chunk
    const int wcol_b = (s3w & 3) * 16;         // byte col within 64-B row

    const signed char* __restrict__ Ag = A + (size_t)brow * K;
    const signed char* __restrict__ Bg = B + (size_t)bcol * K;

    i32x4 acc[8][4];
#pragma unroll
    for (int m = 0; m < 8; ++m)
#pragma unroll
        for (int n = 0; n < 4; ++n) acc[m][n] = (i32x4)(0);

    i32x4 afL[4], afH[4], bfv[4];

#define STG1(dst, src) __builtin_amdgcn_global_load_lds(GLOBAL_AS(src), LDS_AS(dst), 16, 0, 0)
#define STGA(slot, j) do {                                                      \
    _Pragma("unroll")                                                           \
    for (int c = 0; c < 2; ++c) {                                               \
        const int q_ = c * 8 + wave;                                            \
        STG1(Au + (slot) * 16384 + q_ * 1024,                                   \
             Ag + (size_t)(q_ * 16 + wrow_l) * K + (j) * 64 + wcol_b);          \
    }                                                                           \
  } while (0)
#define STGB(slot, j) do {                                                      \
    _Pragma("unroll")                                                           \
    for (int c = 0; c < 2; ++c) {                                               \
        const int q_ = c * 8 + wave;                                            \
        STG1(Bu + (slot) * 16384 + q_ * 1024,                                   \
             Bg + (size_t)(q_ * 16 + wrow_l) * K + (j) * 64 + wcol_b);          \
    }                                                                           \
  } while (0)
#define LDA4(buf, unit, m0) do {                                                \
    const unsigned char* ub_ = Au + (unit) * 16384;                             \
    _Pragma("unroll")                                                           \
    for (int i = 0; i < 4; ++i)                                                 \
        buf[i] = *(const i32x4*)(ub_ + abase + ((m0) + i) * 1024);              \
  } while (0)
#define LDB4(buf, unit) do {                                                    \
    const unsigned char* vb_ = Bu + (unit) * 16384;                             \
    _Pragma("unroll")                                                           \
    for (int n = 0; n < 4; ++n)                                                 \
        buf[n] = *(const i32x4*)(vb_ + bbase + n * 1024);                       \
  } while (0)
#define MM16(a, r0) do {                                                        \
    __builtin_amdgcn_s_setprio(1);                                              \
    _Pragma("unroll")                                                           \
    for (int i = 0; i < 4; ++i)                                                 \
      _Pragma("unroll")                                                         \
      for (int n = 0; n < 4; ++n)                                               \
        acc[(r0) + i][n] = __builtin_amdgcn_mfma_i32_16x16x64_i8(               \
            a[i], bfv[n], acc[(r0) + i][n], 0, 0, 0);                           \
    __builtin_amdgcn_s_setprio(0);                                              \
  } while (0)
#define BAR    __builtin_amdgcn_s_barrier()
#define FENCE  asm volatile("" ::: "memory")
#define WVM0   asm volatile("s_waitcnt vmcnt(0)" ::: "memory")

    // prologue: stage tile 0 into slot 0, drain, enter loop
    STGA(0, 0); STGB(0, 0);
    WVM0;
    BAR; FENCE;

#pragma unroll 1
    for (int t = 0; t < NT; ++t) {
        const int s  = t & 1;
        const int s1 = s ^ 1;
        // stage tile t+1 at tile top: ages a full tile before the end drain
        if (t + 1 < NT) { STGA(s1, t + 1); STGB(s1, t + 1); }
        // P1
        LDA4(afL, s, 0); LDB4(bfv, s);
        BAR; FENCE;
        MM16(afL, 0);
        BAR; FENCE;
        // P2
        LDA4(afH, s, 4);
        BAR; FENCE;
        MM16(afH, 4);
        WVM0;              // next tile's stages: issued ~1 full tile ago
        BAR; FENCE;
    }

    // epilogue: C/D layout col=lane&15, row=(lane>>4)*4+reg (dtype-indep,
    // m121-m128); y = acc * sx[row]*sw[col] + bias[col]
    float swv[4], bvv[4];
#pragma unroll
    for (int n = 0; n < 4; ++n) {
        const int col = bcol + wcol + n * 16 + fr;
        swv[n] = sw[col];
        bvv[n] = bias[col];
    }
#pragma unroll
    for (int m = 0; m < 8; ++m) {
#pragma unroll
        for (int j = 0; j < 4; ++j) {
            const int row = brow + wrow + m * 16 + fq * 4 + j;
            const float sxr = sx[row];
            float* crow = C + (size_t)row * N + bcol + wcol + fr;
#pragma unroll
            for (int n = 0; n < 4; ++n)
                crow[n * 16] = (float)acc[m][n][j] * (sxr * swv[n]) + bvv[n];
        }
    }
#undef STG1
#undef STGA
#undef STGB
#undef LDA4
#undef LDB4
#undef MM16
#undef BAR
#undef FENCE
#undef WVM0
}

// ---- fallback (only if ws too small): f32 vector GEMM ----
__global__ void fallback_gemm(const float* __restrict__ x,
                              const float* __restrict__ w,
                              const int* __restrict__ mask,
                              const float* __restrict__ bias,
                              float* __restrict__ C) {
    const int tid = threadIdx.x;
    const int tx = tid & 15, ty = tid >> 4;
    const int brow = blockIdx.y * 64, bcol = blockIdx.x * 64;
    __shared__ float As[64][17];
    __shared__ float Ws[64][17];
    float acc[4][4] = {};
    for (int k0 = 0; k0 < K; k0 += 16) {
        __syncthreads();
        for (int i = tid; i < 64 * 16; i += 256) {
            int r = i >> 4, c = i & 15;
            As[r][c] = x[(size_t)(brow + r) * K + k0 + c];
            float wv = w[(size_t)(bcol + r) * K + k0 + c];
            Ws[r][c] = mask[(size_t)(bcol + r) * K + k0 + c] ? wv : 0.0f;
        }
        __syncthreads();
        for (int kk = 0; kk < 16; ++kk) {
            float a[4], b[4];
#pragma unroll
            for (int i = 0; i < 4; ++i) a[i] = As[ty * 4 + i][kk];
#pragma unroll
            for (int i = 0; i < 4; ++i) b[i] = Ws[tx * 4 + i][kk];
#pragma unroll
            for (int i = 0; i < 4; ++i)
#pragma unroll
                for (int j = 0; j < 4; ++j) acc[i][j] += a[i] * b[j];
        }
    }
    for (int i = 0; i < 4; ++i)
        for (int j = 0; j < 4; ++j) {
            int row = brow + ty * 4 + i, col = bcol + tx * 4 + j;
            C[(size_t)row * N + col] = acc[i][j] + bias[col];
        }
}

extern "C" void kernel_launch(void* const* d_in, const int* in_sizes, int n_in,
                              void* d_out, int out_size, void* d_ws, size_t ws_size,
                              hipStream_t stream) {
    const float* x    = (const float*)d_in[0];
    const float* w    = (const float*)d_in[1];
    const float* bias = (const float*)d_in[2];
    const int*   mask = (const int*)d_in[3];
    float* out = (float*)d_out;

    const size_t xq_b = (size_t)M * K;              // 32 MiB
    const size_t wq_b = (size_t)N * K;              // 16 MiB
    const size_t need = xq_b + wq_b + (M + N) * sizeof(float);
    if (ws_size >= need) {
        signed char* xq = (signed char*)d_ws;
        signed char* wq = xq + xq_b;
        float* sx = (float*)(wq + wq_b);
        float* sw = sx + M;
        (void)hipFuncSetAttribute((const void*)gemmI8,
                                  hipFuncAttributeMaxDynamicSharedMemorySize,
                                  65536);
        quant_x<<<M, 256, 0, stream>>>(x, xq, sx);
        quant_w<<<N, 256, 0, stream>>>(w, mask, wq, sw);
        gemmI8<<<(M / 256) * (N / 256), 512, 65536, stream>>>(
            xq, wq, sx, sw, bias, out);
    } else {
        dim3 g(N / 64, M / 64);
        fallback_gemm<<<g, 256, 0, stream>>>(x, w, mask, bias, out);
    }
}

// Round 13
// 207.030 us; speedup vs baseline: 4.5867x; 4.5867x over previous
//
#include <hip/hip_runtime.h>
#include <hip/hip_bf16.h>
#include <stdint.h>

// ExpanderLinear: y[t,o] = sum_i x[t,i] * (w[o,i]*mask[o,i]) + bias[o]
// M=8192, K=4096, N=4096. f32 in/out. INT8 MFMA path.
// R13 = R12 (ring-2 x 64KB LDS -> 2 blocks/CU) with the register cap fixed:
// __launch_bounds__(512, 2) (R12's (512,4) forced a 256-reg/wave budget ->
// acc spilled to scratch: VGPR 64, WRITE_SIZE 2.5GB, MfmaUtil 5.9%).

typedef __attribute__((ext_vector_type(4))) float f32x4;
typedef __attribute__((ext_vector_type(4))) int   i32x4;

static constexpr int M = 8192;
static constexpr int N = 4096;
static constexpr int K = 4096;
static constexpr int NT = K / 64;      // 64 K-tiles

#define GLOBAL_AS(p) ((const __attribute__((address_space(1))) void*)(p))
#define LDS_AS(p)    ((__attribute__((address_space(3))) void*)(p))

// ---- prep 1: per-row quant of x -> i8 + sx ----
__global__ void __launch_bounds__(256)
quant_x(const float* __restrict__ x, signed char* __restrict__ xq,
        float* __restrict__ sx) {
    const int row = blockIdx.x, tid = threadIdx.x;
    const f32x4* xr = (const f32x4*)(x + (size_t)row * K);
    f32x4 v[4];
    float am = 0.0f;
#pragma unroll
    for (int c = 0; c < 4; ++c) {
        v[c] = xr[c * 256 + tid];
        am = fmaxf(am, fmaxf(fmaxf(fabsf(v[c].x), fabsf(v[c].y)),
                             fmaxf(fabsf(v[c].z), fabsf(v[c].w))));
    }
#pragma unroll
    for (int off = 32; off; off >>= 1) am = fmaxf(am, __shfl_xor(am, off));
    __shared__ float red[4];
    if ((tid & 63) == 0) red[tid >> 6] = am;
    __syncthreads();
    am = fmaxf(fmaxf(red[0], red[1]), fmaxf(red[2], red[3]));
    const float inv = am > 0.0f ? 127.0f / am : 0.0f;
    int* out = (int*)xq + (size_t)row * (K / 4);
#pragma unroll
    for (int c = 0; c < 4; ++c) {
        int q0 = (int)__builtin_rintf(v[c].x * inv) & 255;
        int q1 = (int)__builtin_rintf(v[c].y * inv) & 255;
        int q2 = (int)__builtin_rintf(v[c].z * inv) & 255;
        int q3 = (int)__builtin_rintf(v[c].w * inv) & 255;
        out[c * 256 + tid] = q0 | (q1 << 8) | (q2 << 16) | (q3 << 24);
    }
    if (tid == 0) sx[row] = am * (1.0f / 127.0f);
}

// ---- prep 2: per-row quant of (w*mask) -> i8 + sw ----
__global__ void __launch_bounds__(256)
quant_w(const float* __restrict__ w, const int* __restrict__ mask,
        signed char* __restrict__ wq, float* __restrict__ sw) {
    const int row = blockIdx.x, tid = threadIdx.x;
    const f32x4* wr = (const f32x4*)(w + (size_t)row * K);
    const i32x4* mr = (const i32x4*)(mask + (size_t)row * K);
    f32x4 v[4];
    float am = 0.0f;
#pragma unroll
    for (int c = 0; c < 4; ++c) {
        f32x4 wv = wr[c * 256 + tid];
        i32x4 mv = mr[c * 256 + tid];
        v[c].x = mv.x ? wv.x : 0.0f;
        v[c].y = mv.y ? wv.y : 0.0f;
        v[c].z = mv.z ? wv.z : 0.0f;
        v[c].w = mv.w ? wv.w : 0.0f;
        am = fmaxf(am, fmaxf(fmaxf(fabsf(v[c].x), fabsf(v[c].y)),
                             fmaxf(fabsf(v[c].z), fabsf(v[c].w))));
    }
#pragma unroll
    for (int off = 32; off; off >>= 1) am = fmaxf(am, __shfl_xor(am, off));
    __shared__ float red[4];
    if ((tid & 63) == 0) red[tid >> 6] = am;
    __syncthreads();
    am = fmaxf(fmaxf(red[0], red[1]), fmaxf(red[2], red[3]));
    const float inv = am > 0.0f ? 127.0f / am : 0.0f;
    int* out = (int*)wq + (size_t)row * (K / 4);
#pragma unroll
    for (int c = 0; c < 4; ++c) {
        int q0 = (int)__builtin_rintf(v[c].x * inv) & 255;
        int q1 = (int)__builtin_rintf(v[c].y * inv) & 255;
        int q2 = (int)__builtin_rintf(v[c].z * inv) & 255;
        int q3 = (int)__builtin_rintf(v[c].w * inv) & 255;
        out[c * 256 + tid] = q0 | (q1 << 8) | (q2 << 16) | (q3 << 24);
    }
    if (tid == 0) sw[row] = am * (1.0f / 127.0f);
}

// ---- main GEMM (i8) ----
// LDS: A = 2 units of [256 rows][64 B] (16KB each), B same -> 64 KiB total,
// 2 blocks/CU. Tile t in slot t&1; stage t+1 into slot (t&1)^1 at tile top
// (WAR-safe: slot's reads were consumed before the previous end-barrier).
// WVM0 at tile end waits on loads aged a full tile (~2600 cyc, no stall).
// Per K-tile 2 phases: {reads; BAR; 16 MFMA; BAR} x2 (R6/R11 pacing).
// Swizzle within 128B row-pair: phys3 = (((row&1)<<2)|fq) ^ ((row>>1)&7);
// LDS writes linear (global_load_lds); global SOURCE pre-swizzled (s3w).
__global__ void __launch_bounds__(512, 2)
gemmI8(const signed char* __restrict__ A,   // [M][K] i8
       const signed char* __restrict__ B,   // [N][K] i8
       const float* __restrict__ sx,        // [M]
       const float* __restrict__ sw,        // [N]
       const float* __restrict__ bias,      // [N]
       float* __restrict__ C) {             // [M][N] f32
    extern __shared__ unsigned char lds[];
    unsigned char* __restrict__ Au = lds;            // 2 * 16384 B
    unsigned char* __restrict__ Bu = lds + 32768;    // 2 * 16384 B

    const int tid  = threadIdx.x;
    const int lane = tid & 63;
    const int wave = tid >> 6;

    // T1: XCD-aware bijective swizzle (nwg = 512, % 8 == 0)
    const int bid = blockIdx.x;
    const int swz = (bid & 7) * 64 + (bid >> 3);
    const int brow = (swz >> 4) * 256;         // ntn = 16
    const int bcol = (swz & 15) * 256;

    const int wrow = (wave >> 2) * 128;        // wave output rows
    const int wcol = (wave & 3) * 64;          // wave output cols
    const int fr = lane & 15;                  // fragment row/col
    const int fq = lane >> 4;                  // k-subgroup (16B each)

    // read-side swizzle bases (byte offsets within a 16KB unit)
    const int s3r   = (((fr & 1) << 2) | fq) ^ (fr >> 1);
    const int abase = wrow * 64 + (fr >> 1) * 128 + s3r * 16;   // + m*1024
    const int bbase = wcol * 64 + (fr >> 1) * 128 + s3r * 16;   // + n*1024

    // write-side: lane's linear LDS slot -> logical (row, byte-col) in global
    const int l8 = lane & 7, lh = lane >> 3;
    const int s3w    = l8 ^ lh;
    const int wrow_l = 2 * lh + (s3w >> 2);    // row within 16-row chunk
    const int wcol_b = (s3w & 3) * 16;         // byte col within 64-B row

    const signed char* __restrict__ Ag = A + (size_t)brow * K;
    const signed char* __restrict__ Bg = B + (size_t)bcol * K;

    i32x4 acc[8][4];
#pragma unroll
    for (int m = 0; m < 8; ++m)
#pragma unroll
        for (int n = 0; n < 4; ++n) acc[m][n] = (i32x4)(0);

    i32x4 afL[4], afH[4], bfv[4];

#define STG1(dst, src) __builtin_amdgcn_global_load_lds(GLOBAL_AS(src), LDS_AS(dst), 16, 0, 0)
#define STGA(slot, j) do {                                                      \
    _Pragma("unroll")                                                           \
    for (int c = 0; c < 2; ++c) {                                               \
        const int q_ = c * 8 + wave;                                            \
        STG1(Au + (slot) * 16384 + q_ * 1024,                                   \
             Ag + (size_t)(q_ * 16 + wrow_l) * K + (j) * 64 + wcol_b);          \
    }                                                                           \
  } while (0)
#define STGB(slot, j) do {                                                      \
    _Pragma("unroll")                                                           \
    for (int c = 0; c < 2; ++c) {                                               \
        const int q_ = c * 8 + wave;                                            \
        STG1(Bu + (slot) * 16384 + q_ * 1024,                                   \
             Bg + (size_t)(q_ * 16 + wrow_l) * K + (j) * 64 + wcol_b);          \
    }                                                                           \
  } while (0)
#define LDA4(buf, unit, m0) do {                                                \
    const unsigned char* ub_ = Au + (unit) * 16384;                             \
    _Pragma("unroll")                                                           \
    for (int i = 0; i < 4; ++i)                                                 \
        buf[i] = *(const i32x4*)(ub_ + abase + ((m0) + i) * 1024);              \
  } while (0)
#define LDB4(buf, unit) do {                                                    \
    const unsigned char* vb_ = Bu + (unit) * 16384;                             \
    _Pragma("unroll")                                                           \
    for (int n = 0; n < 4; ++n)                                                 \
        buf[n] = *(const i32x4*)(vb_ + bbase + n * 1024);                       \
  } while (0)
#define MM16(a, r0) do {                                                        \
    __builtin_amdgcn_s_setprio(1);                                              \
    _Pragma("unroll")                                                           \
    for (int i = 0; i < 4; ++i)                                                 \
      _Pragma("unroll")                                                         \
      for (int n = 0; n < 4; ++n)                                               \
        acc[(r0) + i][n] = __builtin_amdgcn_mfma_i32_16x16x64_i8(               \
            a[i], bfv[n], acc[(r0) + i][n], 0, 0, 0);                           \
    __builtin_amdgcn_s_setprio(0);                                              \
  } while (0)
#define BAR    __builtin_amdgcn_s_barrier()
#define FENCE  asm volatile("" ::: "memory")
#define WVM0   asm volatile("s_waitcnt vmcnt(0)" ::: "memory")

    // prologue: stage tile 0 into slot 0, drain, enter loop
    STGA(0, 0); STGB(0, 0);
    WVM0;
    BAR; FENCE;

#pragma unroll 1
    for (int t = 0; t < NT; ++t) {
        const int s  = t & 1;
        const int s1 = s ^ 1;
        // stage tile t+1 at tile top: ages a full tile before the end drain
        if (t + 1 < NT) { STGA(s1, t + 1); STGB(s1, t + 1); }
        // P1
        LDA4(afL, s, 0); LDB4(bfv, s);
        BAR; FENCE;
        MM16(afL, 0);
        BAR; FENCE;
        // P2
        LDA4(afH, s, 4);
        BAR; FENCE;
        MM16(afH, 4);
        WVM0;              // next tile's stages: issued ~1 full tile ago
        BAR; FENCE;
    }

    // epilogue: C/D layout col=lane&15, row=(lane>>4)*4+reg (dtype-indep,
    // m121-m128); y = acc * sx[row]*sw[col] + bias[col]
    float swv[4], bvv[4];
#pragma unroll
    for (int n = 0; n < 4; ++n) {
        const int col = bcol + wcol + n * 16 + fr;
        swv[n] = sw[col];
        bvv[n] = bias[col];
    }
#pragma unroll
    for (int m = 0; m < 8; ++m) {
#pragma unroll
        for (int j = 0; j < 4; ++j) {
            const int row = brow + wrow + m * 16 + fq * 4 + j;
            const float sxr = sx[row];
            float* crow = C + (size_t)row * N + bcol + wcol + fr;
#pragma unroll
            for (int n = 0; n < 4; ++n)
                crow[n * 16] = (float)acc[m][n][j] * (sxr * swv[n]) + bvv[n];
        }
    }
#undef STG1
#undef STGA
#undef STGB
#undef LDA4
#undef LDB4
#undef MM16
#undef BAR
#undef FENCE
#undef WVM0
}

// ---- fallback (only if ws too small): f32 vector GEMM ----
__global__ void fallback_gemm(const float* __restrict__ x,
                              const float* __restrict__ w,
                              const int* __restrict__ mask,
                              const float* __restrict__ bias,
                              float* __restrict__ C) {
    const int tid = threadIdx.x;
    const int tx = tid & 15, ty = tid >> 4;
    const int brow = blockIdx.y * 64, bcol = blockIdx.x * 64;
    __shared__ float As[64][17];
    __shared__ float Ws[64][17];
    float acc[4][4] = {};
    for (int k0 = 0; k0 < K; k0 += 16) {
        __syncthreads();
        for (int i = tid; i < 64 * 16; i += 256) {
            int r = i >> 4, c = i & 15;
            As[r][c] = x[(size_t)(brow + r) * K + k0 + c];
            float wv = w[(size_t)(bcol + r) * K + k0 + c];
            Ws[r][c] = mask[(size_t)(bcol + r) * K + k0 + c] ? wv : 0.0f;
        }
        __syncthreads();
        for (int kk = 0; kk < 16; ++kk) {
            float a[4], b[4];
#pragma unroll
            for (int i = 0; i < 4; ++i) a[i] = As[ty * 4 + i][kk];
#pragma unroll
            for (int i = 0; i < 4; ++i) b[i] = Ws[tx * 4 + i][kk];
#pragma unroll
            for (int i = 0; i < 4; ++i)
#pragma unroll
                for (int j = 0; j < 4; ++j) acc[i][j] += a[i] * b[j];
        }
    }
    for (int i = 0; i < 4; ++i)
        for (int j = 0; j < 4; ++j) {
            int row = brow + ty * 4 + i, col = bcol + tx * 4 + j;
            C[(size_t)row * N + col] = acc[i][j] + bias[col];
        }
}

extern "C" void kernel_launch(void* const* d_in, const int* in_sizes, int n_in,
                              void* d_out, int out_size, void* d_ws, size_t ws_size,
                              hipStream_t stream) {
    const float* x    = (const float*)d_in[0];
    const float* w    = (const float*)d_in[1];
    const float* bias = (const float*)d_in[2];
    const int*   mask = (const int*)d_in[3];
    float* out = (float*)d_out;

    const size_t xq_b = (size_t)M * K;              // 32 MiB
    const size_t wq_b = (size_t)N * K;              // 16 MiB
    const size_t need = xq_b + wq_b + (M + N) * sizeof(float);
    if (ws_size >= need) {
        signed char* xq = (signed char*)d_ws;
        signed char* wq = xq + xq_b;
        float* sx = (float*)(wq + wq_b);
        float* sw = sx + M;
        (void)hipFuncSetAttribute((const void*)gemmI8,
                                  hipFuncAttributeMaxDynamicSharedMemorySize,
                                  65536);
        quant_x<<<M, 256, 0, stream>>>(x, xq, sx);
        quant_w<<<N, 256, 0, stream>>>(w, mask, wq, sw);
        gemmI8<<<(M / 256) * (N / 256), 512, 65536, stream>>>(
            xq, wq, sx, sw, bias, out);
    } else {
        dim3 g(N / 64, M / 64);
        fallback_gemm<<<g, 256, 0, stream>>>(x, w, mask, bias, out);
    }
}